// Round 10
// baseline (149.237 us; speedup 1.0000x reference)
//
#include <hip/hip_runtime.h>
#include <hip/hip_bf16.h>
#include <hip/hip_cooperative_groups.h>

namespace cg = cooperative_groups;

#define BB 4
#define SS 2
#define DD 16
#define CH 32          // S*D
#define PP (512*512)   // pixels per item
#define NSEGC 64
#define MARGINF 0.25f
#define CSTR 33        // centL row stride: bank=(label+ch)%32 -> ~2-way (free)

// ---- fused geometry: 2048 px per block -> grid 512 (co-resident at 3 blk/CU by LDS) ----
#define PXF 2048
#define NBF (PP/PXF)            // 128 per batch
// ---- fallback k_sums geometry ----
#define CHUNK 1024
#define NCHUNK (PP/CHUNK)       // 256 per batch -> grid 1024

typedef __attribute__((ext_vector_type(4))) float  f32x4;
typedef __attribute__((ext_vector_type(8))) short  short8;

__device__ inline short f2bf(float x) {
    union { __hip_bfloat16 h; short s; } u;
    u.h = __float2bfloat16(x);   // RNE
    return u.s;
}

// ================= fused cooperative kernel =================
__global__ __launch_bounds__(256, 2) void k_fused(const float* __restrict__ preds,
                                                  const int* __restrict__ labels,
                                                  float* __restrict__ g_sums,    // [B][CH][NSEG]
                                                  float* __restrict__ g_counts,  // [B][NSEG]
                                                  float* __restrict__ g_pull,    // [B]
                                                  float* __restrict__ g_push,    // [B]
                                                  unsigned* __restrict__ g_done,
                                                  float* __restrict__ out)
{
    __shared__ int   labs[PXF];          // 8 KB
    __shared__ float buf[4][CH][68];     // 34 KB
    __shared__ float cbuf[4][NSEGC];     // 1 KB
    __shared__ float centL[NSEGC * CSTR];// 8.4 KB
    __shared__ float redP[4];
    __shared__ float red[4];

    const int b    = blockIdx.x >> 7;            // / NBF
    const int base = (blockIdx.x & (NBF - 1)) * PXF;
    const int tid  = threadIdx.x;
    const int w    = tid >> 6;
    const int l    = tid & 63;
    const int lm   = l & 15;
    const int lk   = l >> 4;

    // ---------- phase 1: segment sums + counts (one-hot MFMA, R3-proven math) ----------
    ((int4*)labs)[tid]       = ((const int4*)(labels + (size_t)b * PP + base))[tid];
    ((int4*)labs)[256 + tid] = ((const int4*)(labels + (size_t)b * PP + base))[256 + tid];

    f32x4 acc[4][2];
    f32x4 accc[4];
#pragma unroll
    for (int mt = 0; mt < 4; ++mt) {
        accc[mt] = f32x4{0.f, 0.f, 0.f, 0.f};
#pragma unroll
        for (int nt = 0; nt < 2; ++nt) acc[mt][nt] = f32x4{0.f, 0.f, 0.f, 0.f};
    }
    short8 ones;
#pragma unroll
    for (int j = 0; j < 8; ++j) ones[j] = (short)0x3F80;  // bf16 1.0

    __syncthreads();

    const float* pb = preds + (size_t)b * CH * PP + base;

    // wave w owns pixels [w*512, w*512+512): 16 K-chunks of 32
#pragma unroll 2
    for (int c = 0; c < 16; ++c) {
        const int kbase = w * 512 + c * 32 + lk * 8;
        const int4 L0 = *(const int4*)&labs[kbase];
        const int4 L1 = *(const int4*)&labs[kbase + 4];
        const int labv[8] = {L0.x, L0.y, L0.z, L0.w, L1.x, L1.y, L1.z, L1.w};

        short8 af[4];
#pragma unroll
        for (int mt = 0; mt < 4; ++mt) {
            const int target = mt * 16 + lm;
#pragma unroll
            for (int j = 0; j < 8; ++j)
                af[mt][j] = (labv[j] == target) ? (short)0x3F80 : (short)0;
        }

#pragma unroll
        for (int nt = 0; nt < 2; ++nt) {
            const float* src = pb + (size_t)(nt * 16 + lm) * PP + kbase;
            const float4 v0 = ((const float4*)src)[0];
            const float4 v1 = ((const float4*)src)[1];
            short8 bf;
            bf[0] = f2bf(v0.x); bf[1] = f2bf(v0.y); bf[2] = f2bf(v0.z); bf[3] = f2bf(v0.w);
            bf[4] = f2bf(v1.x); bf[5] = f2bf(v1.y); bf[6] = f2bf(v1.z); bf[7] = f2bf(v1.w);
#pragma unroll
            for (int mt = 0; mt < 4; ++mt)
                acc[mt][nt] = __builtin_amdgcn_mfma_f32_16x16x32_bf16(af[mt], bf, acc[mt][nt], 0, 0, 0);
        }
#pragma unroll
        for (int mt = 0; mt < 4; ++mt)
            accc[mt] = __builtin_amdgcn_mfma_f32_16x16x32_bf16(af[mt], ones, accc[mt], 0, 0, 0);
    }

    // D layout: col = lane&15, row = (lane>>4)*4 + reg (m89-verified)
#pragma unroll
    for (int mt = 0; mt < 4; ++mt) {
#pragma unroll
        for (int nt = 0; nt < 2; ++nt)
            *(f32x4*)&buf[w][nt * 16 + lm][mt * 16 + lk * 4] = acc[mt][nt];
        if (lm == 0)
            *(f32x4*)&cbuf[w][mt * 16 + lk * 4] = accc[mt];
    }
    __syncthreads();

    for (int i = tid; i < CH * NSEGC; i += 256) {
        const int col = i >> 6, row = i & 63;   // i = ch*64 + seg
        const float s = buf[0][col][row] + buf[1][col][row] + buf[2][col][row] + buf[3][col][row];
        atomicAdd(&g_sums[(size_t)b * CH * NSEGC + i], s);
    }
    if (tid < NSEGC)
        atomicAdd(&g_counts[b * NSEGC + tid],
                  cbuf[0][tid] + cbuf[1][tid] + cbuf[2][tid] + cbuf[3][tid]);

    __threadfence();
    cg::this_grid().sync();

    // ---------- phase 2: per-block centroids (coalesced), push (4 blocks), pull ----------
    if (tid < NSEGC) cbuf[0][tid] = fmaxf(g_counts[b * NSEGC + tid], 1.0f);
    __syncthreads();
#pragma unroll
    for (int k = 0; k < 8; ++k) {
        const int idx = tid * 8 + k;            // ch-major: ch=idx>>6, seg=idx&63
        const int ch = idx >> 6, seg = idx & 63;
        centL[seg * CSTR + ch] = g_sums[(size_t)b * CH * NSEGC + idx] / cbuf[0][seg];
    }
    __syncthreads();

    if ((blockIdx.x & (NBF - 1)) == 0) {        // push: one block per batch (R5-proven body)
        float acc_p = 0.f;
        for (int t = tid; t < SS * 2016; t += 256) {
            const int s = t / 2016;
            int rem = t % 2016;
            int i = 0;
            while (rem >= 63 - i) { rem -= 63 - i; ++i; }
            const int j = i + 1 + rem;
            float dsum = 0.f;
#pragma unroll
            for (int d = 0; d < DD; ++d) {
                const int ch = s * DD + d;
                dsum += fabsf(centL[i * CSTR + ch] - centL[j * CSTR + ch]);
            }
            const float cd = dsum * (1.f / DD);
            const float r = fmaxf(MARGINF - cd, 0.f);
            acc_p += r * r;
        }
        for (int o = 32; o > 0; o >>= 1) acc_p += __shfl_down(acc_p, o, 64);
        if ((tid & 63) == 0) redP[tid >> 6] = acc_p;
        __syncthreads();
        if (tid == 0)
            atomicAdd(&g_push[b], (redP[0] + redP[1] + redP[2] + redP[3]) * (1.0f / (SS * 2016)));
    }

    // pull: 8 px/thread, per-channel 1 KB-contiguous wave loads (L3-hot after phase 1)
    const int* lp = labels + (size_t)b * PP + base + tid * 8;
    const int4 L0 = ((const int4*)lp)[0];
    const int4 L1 = ((const int4*)lp)[1];
    const int coff[8] = {L0.x * CSTR, L0.y * CSTR, L0.z * CSTR, L0.w * CSTR,
                         L1.x * CSTR, L1.y * CSTR, L1.z * CSTR, L1.w * CSTR};

    float a0[8], a1[8];
#pragma unroll
    for (int j = 0; j < 8; ++j) { a0[j] = 0.f; a1[j] = 0.f; }

    const float* pbase = preds + (size_t)b * CH * PP + base + tid * 8;
#pragma unroll
    for (int ch = 0; ch < CH; ++ch) {
        const float4 v0 = ((const float4*)(pbase + (size_t)ch * PP))[0];
        const float4 v1 = ((const float4*)(pbase + (size_t)ch * PP))[1];
        float* aa = (ch < 16) ? a0 : a1;
        aa[0] += fabsf(v0.x - centL[coff[0] + ch]);
        aa[1] += fabsf(v0.y - centL[coff[1] + ch]);
        aa[2] += fabsf(v0.z - centL[coff[2] + ch]);
        aa[3] += fabsf(v0.w - centL[coff[3] + ch]);
        aa[4] += fabsf(v1.x - centL[coff[4] + ch]);
        aa[5] += fabsf(v1.y - centL[coff[5] + ch]);
        aa[6] += fabsf(v1.z - centL[coff[6] + ch]);
        aa[7] += fabsf(v1.w - centL[coff[7] + ch]);
    }
    float total = 0.f;
#pragma unroll
    for (int j = 0; j < 8; ++j) {
        float q;
        q = a0[j] * (1.f / DD); total += q * q;
        q = a1[j] * (1.f / DD); total += q * q;
    }
    for (int o = 32; o > 0; o >>= 1) total += __shfl_down(total, o, 64);
    if ((tid & 63) == 0) red[tid >> 6] = total;
    __syncthreads();

    if (tid == 0) {
        atomicAdd(&g_pull[b], red[0] + red[1] + red[2] + red[3]);
        __threadfence();
        const unsigned prev = atomicAdd(g_done, 1u);
        if (prev == gridDim.x - 1) {
            float accf = 0.f;
            for (int bb = 0; bb < BB; ++bb) {
                const float pu = atomicAdd(&g_pull[bb], 0.0f);   // coherent reads
                const float ph = atomicAdd(&g_push[bb], 0.0f);
                accf += ph + 0.1f * (pu * (1.0f / (SS * PP)));
            }
            out[0] = accf * (1.0f / BB);
        }
    }
}

// ================= fallback path (no cooperative launch) =================
__global__ __launch_bounds__(256) void k_sums(const float* __restrict__ preds,
                                              const int* __restrict__ labels,
                                              float* __restrict__ g_sums,
                                              float* __restrict__ g_counts)
{
    __shared__ int   labs[CHUNK];
    __shared__ float buf[4][CH][68];
    __shared__ float cbuf[4][NSEGC];

    const int b    = blockIdx.x / NCHUNK;
    const int base = (blockIdx.x % NCHUNK) * CHUNK;
    const int tid  = threadIdx.x;
    const int w    = tid >> 6;
    const int l    = tid & 63;
    const int lm   = l & 15;
    const int lk   = l >> 4;

    ((int4*)labs)[tid] = ((const int4*)(labels + (size_t)b * PP + base))[tid];

    f32x4 acc[4][2];
    f32x4 accc[4];
#pragma unroll
    for (int mt = 0; mt < 4; ++mt) {
        accc[mt] = f32x4{0.f, 0.f, 0.f, 0.f};
#pragma unroll
        for (int nt = 0; nt < 2; ++nt) acc[mt][nt] = f32x4{0.f, 0.f, 0.f, 0.f};
    }
    short8 ones;
#pragma unroll
    for (int j = 0; j < 8; ++j) ones[j] = (short)0x3F80;

    __syncthreads();

    const float* pb = preds + (size_t)b * CH * PP + base;

#pragma unroll 2
    for (int c = 0; c < 8; ++c) {
        const int kbase = (w * 8 + c) * 32 + lk * 8;
        const int4 L0 = *(const int4*)&labs[kbase];
        const int4 L1 = *(const int4*)&labs[kbase + 4];
        const int labv[8] = {L0.x, L0.y, L0.z, L0.w, L1.x, L1.y, L1.z, L1.w};

        short8 af[4];
#pragma unroll
        for (int mt = 0; mt < 4; ++mt) {
            const int target = mt * 16 + lm;
#pragma unroll
            for (int j = 0; j < 8; ++j)
                af[mt][j] = (labv[j] == target) ? (short)0x3F80 : (short)0;
        }
#pragma unroll
        for (int nt = 0; nt < 2; ++nt) {
            const float* src = pb + (size_t)(nt * 16 + lm) * PP + kbase;
            const float4 v0 = ((const float4*)src)[0];
            const float4 v1 = ((const float4*)src)[1];
            short8 bf;
            bf[0] = f2bf(v0.x); bf[1] = f2bf(v0.y); bf[2] = f2bf(v0.z); bf[3] = f2bf(v0.w);
            bf[4] = f2bf(v1.x); bf[5] = f2bf(v1.y); bf[6] = f2bf(v1.z); bf[7] = f2bf(v1.w);
#pragma unroll
            for (int mt = 0; mt < 4; ++mt)
                acc[mt][nt] = __builtin_amdgcn_mfma_f32_16x16x32_bf16(af[mt], bf, acc[mt][nt], 0, 0, 0);
        }
#pragma unroll
        for (int mt = 0; mt < 4; ++mt)
            accc[mt] = __builtin_amdgcn_mfma_f32_16x16x32_bf16(af[mt], ones, accc[mt], 0, 0, 0);
    }

#pragma unroll
    for (int mt = 0; mt < 4; ++mt) {
#pragma unroll
        for (int nt = 0; nt < 2; ++nt)
            *(f32x4*)&buf[w][nt * 16 + lm][mt * 16 + lk * 4] = acc[mt][nt];
        if (lm == 0)
            *(f32x4*)&cbuf[w][mt * 16 + lk * 4] = accc[mt];
    }
    __syncthreads();

    for (int i = tid; i < CH * NSEGC; i += 256) {
        const int col = i >> 6, row = i & 63;
        const float s = buf[0][col][row] + buf[1][col][row] + buf[2][col][row] + buf[3][col][row];
        atomicAdd(&g_sums[(size_t)b * CH * NSEGC + i], s);
    }
    if (tid < NSEGC)
        atomicAdd(&g_counts[b * NSEGC + tid],
                  cbuf[0][tid] + cbuf[1][tid] + cbuf[2][tid] + cbuf[3][tid]);
}

__global__ __launch_bounds__(256) void k_push(const float* __restrict__ g_sums,
                                              const float* __restrict__ g_counts,
                                              float* __restrict__ g_cent,   // [B][NSEG][CH]
                                              float* __restrict__ g_push)
{
    __shared__ float centB[CH * NSEGC];
    __shared__ float red[4];
    const int b = blockIdx.x;
    const int tid = threadIdx.x;

    for (int i = tid; i < CH * NSEGC; i += 256) {
        const int ch = i >> 6, seg = i & 63;
        const float cnt = fmaxf(g_counts[b * NSEGC + seg], 1.0f);
        const float c = g_sums[(size_t)b * CH * NSEGC + i] / cnt;
        centB[i] = c;
        g_cent[(size_t)b * NSEGC * CH + seg * CH + ch] = c;
    }
    __syncthreads();

    float acc = 0.f;
    for (int t = tid; t < SS * 2016; t += 256) {
        const int s = t / 2016;
        int rem = t % 2016;
        int i = 0;
        while (rem >= 63 - i) { rem -= 63 - i; ++i; }
        const int j = i + 1 + rem;
        float dsum = 0.f;
#pragma unroll
        for (int d = 0; d < DD; ++d) {
            const int ch = s * DD + d;
            dsum += fabsf(centB[ch * NSEGC + i] - centB[ch * NSEGC + j]);
        }
        const float cd = dsum * (1.f / DD);
        const float r = fmaxf(MARGINF - cd, 0.f);
        acc += r * r;
    }
    for (int o = 32; o > 0; o >>= 1) acc += __shfl_down(acc, o, 64);
    if ((tid & 63) == 0) red[tid >> 6] = acc;
    __syncthreads();
    if (tid == 0)
        g_push[b] = (red[0] + red[1] + red[2] + red[3]) * (1.0f / (SS * 2016));
}

__global__ __launch_bounds__(256) void k_pull_fb(const float* __restrict__ preds,
                                                 const int* __restrict__ labels,
                                                 const float* __restrict__ g_cent,
                                                 float* __restrict__ g_pull,
                                                 const float* __restrict__ g_push,
                                                 unsigned* __restrict__ g_done,
                                                 float* __restrict__ out)
{
    __shared__ float centL[NSEGC * CSTR];
    __shared__ float red[4];
    const int b    = blockIdx.x >> 7;               // / NBF
    const int base = (blockIdx.x & (NBF - 1)) * PXF;
    const int tid  = threadIdx.x;

    for (int i = tid; i < NSEGC * CH; i += 256) {
        const int seg = i >> 5, ch = i & 31;
        centL[seg * CSTR + ch] = g_cent[(size_t)b * NSEGC * CH + i];
    }
    const int* lp = labels + (size_t)b * PP + base + tid * 8;
    const int4 L0 = ((const int4*)lp)[0];
    const int4 L1 = ((const int4*)lp)[1];
    const int coff[8] = {L0.x * CSTR, L0.y * CSTR, L0.z * CSTR, L0.w * CSTR,
                         L1.x * CSTR, L1.y * CSTR, L1.z * CSTR, L1.w * CSTR};
    __syncthreads();

    float a0[8], a1[8];
#pragma unroll
    for (int j = 0; j < 8; ++j) { a0[j] = 0.f; a1[j] = 0.f; }

    const float* pbase = preds + (size_t)b * CH * PP + base + tid * 8;
#pragma unroll
    for (int ch = 0; ch < CH; ++ch) {
        const float4 v0 = ((const float4*)(pbase + (size_t)ch * PP))[0];
        const float4 v1 = ((const float4*)(pbase + (size_t)ch * PP))[1];
        float* aa = (ch < 16) ? a0 : a1;
        aa[0] += fabsf(v0.x - centL[coff[0] + ch]);
        aa[1] += fabsf(v0.y - centL[coff[1] + ch]);
        aa[2] += fabsf(v0.z - centL[coff[2] + ch]);
        aa[3] += fabsf(v0.w - centL[coff[3] + ch]);
        aa[4] += fabsf(v1.x - centL[coff[4] + ch]);
        aa[5] += fabsf(v1.y - centL[coff[5] + ch]);
        aa[6] += fabsf(v1.z - centL[coff[6] + ch]);
        aa[7] += fabsf(v1.w - centL[coff[7] + ch]);
    }
    float total = 0.f;
#pragma unroll
    for (int j = 0; j < 8; ++j) {
        float q;
        q = a0[j] * (1.f / DD); total += q * q;
        q = a1[j] * (1.f / DD); total += q * q;
    }
    for (int o = 32; o > 0; o >>= 1) total += __shfl_down(total, o, 64);
    if ((tid & 63) == 0) red[tid >> 6] = total;
    __syncthreads();

    if (tid == 0) {
        atomicAdd(&g_pull[b], red[0] + red[1] + red[2] + red[3]);
        __threadfence();
        const unsigned prev = atomicAdd(g_done, 1u);
        if (prev == gridDim.x - 1) {
            float accf = 0.f;
            for (int bb = 0; bb < BB; ++bb) {
                const float pu = atomicAdd(&g_pull[bb], 0.0f);
                const float ph = g_push[bb];
                accf += ph + 0.1f * (pu * (1.0f / (SS * PP)));
            }
            out[0] = accf * (1.0f / BB);
        }
    }
}

extern "C" void kernel_launch(void* const* d_in, const int* in_sizes, int n_in,
                              void* d_out, int out_size, void* d_ws, size_t ws_size,
                              hipStream_t stream) {
    const float* preds  = (const float*)d_in[0];
    const int*   labels = (const int*)d_in[1];

    float* ws       = (float*)d_ws;
    float* g_sums   = ws;                              // B*CH*NSEG = 8192
    float* g_counts = g_sums + BB * CH * NSEGC;        // 256
    float* g_pull   = g_counts + BB * NSEGC;           // 4
    float* g_push   = g_pull + BB;                     // 4
    unsigned* g_done = (unsigned*)(g_push + BB);       // 1
    float* g_cent   = (float*)(g_done + 1);            // 8192 (fallback only)
    float* outp     = (float*)d_out;

    // zero accumulated region (sums, counts, pull, push, done) — replays must not accumulate
    hipMemsetAsync(d_ws, 0,
                   (size_t)(BB * CH * NSEGC + BB * NSEGC + BB + BB + 1) * sizeof(float),
                   stream);

    void* kargs[] = {(void*)&preds, (void*)&labels, (void*)&g_sums, (void*)&g_counts,
                     (void*)&g_pull, (void*)&g_push, (void*)&g_done, (void*)&outp};
    hipError_t e = hipLaunchCooperativeKernel((const void*)k_fused, dim3(BB * NBF), dim3(256),
                                              kargs, 0, stream);
    if (e != hipSuccess) {
        // fallback: proven 3-kernel pipeline
        k_sums   <<<BB * NCHUNK, 256, 0, stream>>>(preds, labels, g_sums, g_counts);
        k_push   <<<BB, 256, 0, stream>>>(g_sums, g_counts, g_cent, g_push);
        k_pull_fb<<<BB * NBF, 256, 0, stream>>>(preds, labels, g_cent, g_pull, g_push,
                                                g_done, outp);
    }
}

// Round 11
// 104.042 us; speedup vs baseline: 1.4344x; 1.4344x over previous
//
#include <hip/hip_runtime.h>
#include <hip/hip_bf16.h>

#define BB 4
#define SS 2
#define DD 16
#define CH 32          // S*D
#define PP (512*512)   // pixels per item
#define NSEGC 64
#define MARGINF 0.25f
#define CSTR 33        // centL row stride: bank=(label+ch)%32 -> ~2-way (free)

// ---- k_sums geometry: 1024 px per block, grid 1024 ----
#define CHUNK 1024
#define NCHUNK (PP/CHUNK)
// ---- k_pull geometry: 2048 px per block, grid 512 ----
#define PXF 2048
#define NBF (PP/PXF)

typedef __attribute__((ext_vector_type(4))) float  f32x4;
typedef __attribute__((ext_vector_type(8))) short  short8;

__device__ inline short f2bf(float x) {
    union { __hip_bfloat16 h; short s; } u;
    u.h = __float2bfloat16(x);   // RNE
    return u.s;
}

// ---------------- kernel A: segment sums + counts via one-hot MFMA ----------------
// 2-stage load pipeline: chunk c+1's 4 float4 issued before chunk c is consumed.
__global__ __launch_bounds__(256) void k_sums(const float* __restrict__ preds,
                                              const int* __restrict__ labels,
                                              float* __restrict__ g_sums,    // [B][CH][NSEG]
                                              float* __restrict__ g_counts)  // [B][NSEG]
{
    __shared__ int   labs[CHUNK];
    __shared__ float buf[4][CH][68];     // per-wave result, [ch][seg(64)+pad]
    __shared__ float cbuf[4][NSEGC];

    const int b    = blockIdx.x / NCHUNK;
    const int base = (blockIdx.x % NCHUNK) * CHUNK;
    const int tid  = threadIdx.x;
    const int w    = tid >> 6;           // wave 0..3
    const int l    = tid & 63;
    const int lm   = l & 15;             // A-row / B-col / D-col
    const int lk   = l >> 4;             // k-group

    ((int4*)labs)[tid] = ((const int4*)(labels + (size_t)b * PP + base))[tid];

    f32x4 acc[4][2];
    f32x4 accc[4];
#pragma unroll
    for (int mt = 0; mt < 4; ++mt) {
        accc[mt] = f32x4{0.f, 0.f, 0.f, 0.f};
#pragma unroll
        for (int nt = 0; nt < 2; ++nt) acc[mt][nt] = f32x4{0.f, 0.f, 0.f, 0.f};
    }
    short8 ones;
#pragma unroll
    for (int j = 0; j < 8; ++j) ones[j] = (short)0x3F80;  // bf16 1.0

    __syncthreads();

    const float* pb  = preds + (size_t)b * CH * PP + base;
    const float* pb0 = pb + (size_t)lm * PP;          // channel lm
    const float* pb1 = pb + (size_t)(16 + lm) * PP;   // channel lm+16

    float4 q[2][2][2];    // [stage][nt][half]
#define LOADC(c, s) { \
        const int kb_ = ((w) * 8 + (c)) * 32 + lk * 8; \
        q[s][0][0] = *(const float4*)(pb0 + kb_); \
        q[s][0][1] = *(const float4*)(pb0 + kb_ + 4); \
        q[s][1][0] = *(const float4*)(pb1 + kb_); \
        q[s][1][1] = *(const float4*)(pb1 + kb_ + 4); }

    LOADC(0, 0)
#pragma unroll
    for (int c = 0; c < 8; ++c) {
        const int s = c & 1;
        if (c < 7) LOADC(c + 1, s ^ 1)    // next chunk's loads in flight during consume

        const int kb = (w * 8 + c) * 32 + lk * 8;
        const int4 L0 = *(const int4*)&labs[kb];
        const int4 L1 = *(const int4*)&labs[kb + 4];
        const int labv[8] = {L0.x, L0.y, L0.z, L0.w, L1.x, L1.y, L1.z, L1.w};

        short8 af[4];
#pragma unroll
        for (int mt = 0; mt < 4; ++mt) {
            const int target = mt * 16 + lm;
#pragma unroll
            for (int j = 0; j < 8; ++j)
                af[mt][j] = (labv[j] == target) ? (short)0x3F80 : (short)0;
        }

#pragma unroll
        for (int nt = 0; nt < 2; ++nt) {
            const float4 v0 = q[s][nt][0];
            const float4 v1 = q[s][nt][1];
            short8 bf;
            bf[0] = f2bf(v0.x); bf[1] = f2bf(v0.y); bf[2] = f2bf(v0.z); bf[3] = f2bf(v0.w);
            bf[4] = f2bf(v1.x); bf[5] = f2bf(v1.y); bf[6] = f2bf(v1.z); bf[7] = f2bf(v1.w);
#pragma unroll
            for (int mt = 0; mt < 4; ++mt)
                acc[mt][nt] = __builtin_amdgcn_mfma_f32_16x16x32_bf16(af[mt], bf, acc[mt][nt], 0, 0, 0);
        }
#pragma unroll
        for (int mt = 0; mt < 4; ++mt)
            accc[mt] = __builtin_amdgcn_mfma_f32_16x16x32_bf16(af[mt], ones, accc[mt], 0, 0, 0);
    }
#undef LOADC

    // D layout: col = lane&15, row = (lane>>4)*4 + reg  (m89-verified)
#pragma unroll
    for (int mt = 0; mt < 4; ++mt) {
#pragma unroll
        for (int nt = 0; nt < 2; ++nt)
            *(f32x4*)&buf[w][nt * 16 + lm][mt * 16 + lk * 4] = acc[mt][nt];
        if (lm == 0)
            *(f32x4*)&cbuf[w][mt * 16 + lk * 4] = accc[mt];
    }
    __syncthreads();

    for (int i = tid; i < CH * NSEGC; i += 256) {
        const int col = i >> 6, row = i & 63;   // i = ch*64 + seg
        const float s = buf[0][col][row] + buf[1][col][row] + buf[2][col][row] + buf[3][col][row];
        atomicAdd(&g_sums[(size_t)b * CH * NSEGC + i], s);
    }
    if (tid < NSEGC)
        atomicAdd(&g_counts[b * NSEGC + tid],
                  cbuf[0][tid] + cbuf[1][tid] + cbuf[2][tid] + cbuf[3][tid]);
}

// ---------------- kernel B: centroids + push loss (one block per batch) ----------------
__global__ __launch_bounds__(256) void k_push(const float* __restrict__ g_sums,
                                              const float* __restrict__ g_counts,
                                              float* __restrict__ g_cent,   // [B][NSEG][CH]
                                              float* __restrict__ g_push)   // [B]
{
    __shared__ float centB[CH * NSEGC];  // [ch][seg]
    __shared__ float red[4];
    const int b = blockIdx.x;
    const int tid = threadIdx.x;

    for (int i = tid; i < CH * NSEGC; i += 256) {
        const int ch = i >> 6, seg = i & 63;
        const float cnt = fmaxf(g_counts[b * NSEGC + seg], 1.0f);
        const float c = g_sums[(size_t)b * CH * NSEGC + i] / cnt;
        centB[i] = c;
        g_cent[(size_t)b * NSEGC * CH + seg * CH + ch] = c;
    }
    __syncthreads();

    float acc = 0.f;
    for (int t = tid; t < SS * 2016; t += 256) {
        const int s = t / 2016;
        int rem = t % 2016;
        int i = 0;
        while (rem >= 63 - i) { rem -= 63 - i; ++i; }
        const int j = i + 1 + rem;
        float dsum = 0.f;
#pragma unroll
        for (int d = 0; d < DD; ++d) {
            const int ch = s * DD + d;
            dsum += fabsf(centB[ch * NSEGC + i] - centB[ch * NSEGC + j]);
        }
        const float cd = dsum * (1.f / DD);
        const float r = fmaxf(MARGINF - cd, 0.f);
        acc += r * r;
    }
    for (int o = 32; o > 0; o >>= 1) acc += __shfl_down(acc, o, 64);
    if ((tid & 63) == 0) red[tid >> 6] = acc;
    __syncthreads();
    if (tid == 0)
        g_push[b] = (red[0] + red[1] + red[2] + red[3]) * (1.0f / (SS * 2016));
}

// ---------------- kernel C: pull loss + last-block finalize ----------------
// 2048 px/block in two contiguous 1024-px quarters; every wave load = 1 KB contiguous.
// 4-channel-deep prefetch ring (8 float4 in flight/thread).
__global__ __launch_bounds__(256) void k_pull(const float* __restrict__ preds,
                                              const int* __restrict__ labels,
                                              const float* __restrict__ g_cent, // [B][NSEG][CH]
                                              float* __restrict__ g_pull,       // [B]
                                              const float* __restrict__ g_push, // [B]
                                              unsigned* __restrict__ g_done,
                                              float* __restrict__ out)
{
    __shared__ float centL[NSEGC * CSTR];   // [seg][ch]
    __shared__ float red[4];
    const int b    = blockIdx.x / NBF;
    const int base = (blockIdx.x % NBF) * PXF;
    const int tid  = threadIdx.x;

    for (int i = tid; i < NSEGC * CH; i += 256) {
        const int seg = i >> 5, ch = i & 31;
        centL[seg * CSTR + ch] = g_cent[(size_t)b * NSEGC * CH + i];  // coalesced
    }
    // this thread's 8 pixels: 4 at base+tid*4, 4 at base+1024+tid*4 (both wave-contiguous)
    const int4 lA = ((const int4*)(labels + (size_t)b * PP + base))[tid];
    const int4 lB = ((const int4*)(labels + (size_t)b * PP + base + 1024))[tid];
    const int cA[4] = {lA.x * CSTR, lA.y * CSTR, lA.z * CSTR, lA.w * CSTR};
    const int cB[4] = {lB.x * CSTR, lB.y * CSTR, lB.z * CSTR, lB.w * CSTR};
    __syncthreads();

    const float* pc = preds + (size_t)b * CH * PP + base;

    float aA0[4], aA1[4], aB0[4], aB1[4];
#pragma unroll
    for (int j = 0; j < 4; ++j) { aA0[j] = aA1[j] = aB0[j] = aB1[j] = 0.f; }

    float4 uA[4], uB[4];   // 4-channel prefetch ring
#define LDCH(k, ch) { \
        uA[k] = ((const float4*)(pc + (size_t)(ch) * PP))[tid]; \
        uB[k] = ((const float4*)(pc + (size_t)(ch) * PP + 1024))[tid]; }
#pragma unroll
    for (int k = 0; k < 4; ++k) LDCH(k, k)

#pragma unroll
    for (int ch = 0; ch < CH; ++ch) {
        const int k = ch & 3;
        const float4 vA = uA[k];
        const float4 vB = uB[k];
        if (ch < CH - 4) LDCH(k, ch + 4)
        if (ch < 16) {
            aA0[0] += fabsf(vA.x - centL[cA[0] + ch]);
            aA0[1] += fabsf(vA.y - centL[cA[1] + ch]);
            aA0[2] += fabsf(vA.z - centL[cA[2] + ch]);
            aA0[3] += fabsf(vA.w - centL[cA[3] + ch]);
            aB0[0] += fabsf(vB.x - centL[cB[0] + ch]);
            aB0[1] += fabsf(vB.y - centL[cB[1] + ch]);
            aB0[2] += fabsf(vB.z - centL[cB[2] + ch]);
            aB0[3] += fabsf(vB.w - centL[cB[3] + ch]);
        } else {
            aA1[0] += fabsf(vA.x - centL[cA[0] + ch]);
            aA1[1] += fabsf(vA.y - centL[cA[1] + ch]);
            aA1[2] += fabsf(vA.z - centL[cA[2] + ch]);
            aA1[3] += fabsf(vA.w - centL[cA[3] + ch]);
            aB1[0] += fabsf(vB.x - centL[cB[0] + ch]);
            aB1[1] += fabsf(vB.y - centL[cB[1] + ch]);
            aB1[2] += fabsf(vB.z - centL[cB[2] + ch]);
            aB1[3] += fabsf(vB.w - centL[cB[3] + ch]);
        }
    }
#undef LDCH

    float total = 0.f;
#pragma unroll
    for (int j = 0; j < 4; ++j) {
        float q;
        q = aA0[j] * (1.f / DD); total += q * q;
        q = aA1[j] * (1.f / DD); total += q * q;
        q = aB0[j] * (1.f / DD); total += q * q;
        q = aB1[j] * (1.f / DD); total += q * q;
    }
    for (int o = 32; o > 0; o >>= 1) total += __shfl_down(total, o, 64);
    if ((tid & 63) == 0) red[tid >> 6] = total;
    __syncthreads();

    if (tid == 0) {
        atomicAdd(&g_pull[b], red[0] + red[1] + red[2] + red[3]);
        __threadfence();
        const unsigned prev = atomicAdd(g_done, 1u);
        if (prev == gridDim.x - 1) {
            float accf = 0.f;
            for (int bb = 0; bb < BB; ++bb) {
                const float pu = atomicAdd(&g_pull[bb], 0.0f);   // coherent read
                const float ph = g_push[bb];                     // written by prior kernel
                accf += ph + 0.1f * (pu * (1.0f / (SS * PP)));
            }
            out[0] = accf * (1.0f / BB);
        }
    }
}

extern "C" void kernel_launch(void* const* d_in, const int* in_sizes, int n_in,
                              void* d_out, int out_size, void* d_ws, size_t ws_size,
                              hipStream_t stream) {
    const float* preds  = (const float*)d_in[0];
    const int*   labels = (const int*)d_in[1];

    float* ws       = (float*)d_ws;
    float* g_sums   = ws;                              // B*CH*NSEG = 8192
    float* g_counts = g_sums + BB * CH * NSEGC;        // 256
    float* g_pull   = g_counts + BB * NSEGC;           // 4
    float* g_push   = g_pull + BB;                     // 4
    unsigned* g_done = (unsigned*)(g_push + BB);       // 1
    float* g_cent   = (float*)(g_done + 1);            // 8192

    // zero accumulated region (sums, counts, pull, push, done) — replays must not accumulate
    hipMemsetAsync(d_ws, 0,
                   (size_t)(BB * CH * NSEGC + BB * NSEGC + BB + BB + 1) * sizeof(float),
                   stream);

    k_sums<<<BB * NCHUNK, 256, 0, stream>>>(preds, labels, g_sums, g_counts);
    k_push<<<BB, 256, 0, stream>>>(g_sums, g_counts, g_cent, g_push);
    k_pull<<<BB * NBF, 256, 0, stream>>>(preds, labels, g_cent, g_pull, g_push,
                                         g_done, (float*)d_out);
}